// Round 1
// baseline (648.092 us; speedup 1.0000x reference)
//
#include <hip/hip_runtime.h>
#include <hip/hip_bf16.h>

typedef __attribute__((ext_vector_type(8))) short short8;
typedef __attribute__((ext_vector_type(4))) float f32x4;

#define LRELU_SLOPE 0.2f
#define ACT_GAIN 1.41421356237309515f
#define WG_RGB 0.04419417382415922f   // 1/sqrt(512)

__device__ __forceinline__ void glds16(const short* g, short* l) {
    __builtin_amdgcn_global_load_lds(
        (const __attribute__((address_space(1))) unsigned int*)g,
        (__attribute__((address_space(3))) unsigned int*)l, 16, 0, 0);
}

// ---------------- P0: zero Ypad border + init img to rgb_b
__global__ void k_init(__hip_bfloat16* __restrict__ Ypad,
                       const float* __restrict__ rgb_b, float* __restrict__ img) {
    int blk = blockIdx.x, tid = threadIdx.x;
    if (blk < 1040) {                       // border: 4160 slots, 4 per block
        int gslot = blk*4 + (tid >> 6);
        int b = gslot / 260;
        int cell = gslot - b*260;
        int h, w;
        if (cell < 66)       { h = 0;          w = cell; }
        else if (cell < 132) { h = 65;         w = cell - 66; }
        else if (cell < 196) { h = cell - 131; w = 0; }
        else                 { h = cell - 195; w = 65; }
        short8 z = {};
        *(short8*)((short*)Ypad + (((b*66 + h)*66) + w)*512 + (tid & 63)*8) = z;
    } else {                                // img init: 48 blocks x 4 f32x4 (49152 f32x4 total)
        int blk2 = blk - 1040;
        #pragma unroll
        for (int j = 0; j < 4; ++j) {
            int f4 = blk2*1024 + j*256 + tid;   // 0..49151 (f32x4 units)
            int b3 = f4 >> 10;                  // plane = 1024 f32x4
            int o3 = b3 % 3;
            float v = rgb_b[o3];
            f32x4 vv = {v, v, v, v};
            *(f32x4*)(img + f4*4) = vv;
        }
    }
}

// ---------------- P1: styles  s = ws[:,0]@caw^T + cab ;  s2 = (ws[:,1]@raw^T + rab)*wg
__global__ void k_styles(const float* __restrict__ wsin,
                         const float* __restrict__ caw, const float* __restrict__ cab,
                         const float* __restrict__ raw_, const float* __restrict__ rab,
                         float* __restrict__ sbuf, float* __restrict__ s2buf) {
    int b = blockIdx.x, which = blockIdx.y;
    int tid = threadIdx.x, lane = tid & 63, wv = tid >> 6;
    const float* aw = which ? raw_ : caw;
    const float* ab = which ? rab : cab;
    float scale = which ? WG_RGB : 1.0f;
    float* op = which ? s2buf : sbuf;
    __shared__ float wsv[512];
    wsv[tid]       = wsin[(b*2 + which)*512 + tid];
    wsv[tid + 256] = wsin[(b*2 + which)*512 + tid + 256];
    __syncthreads();
    for (int c = wv; c < 512; c += 4) {
        float p = 0.f;
        #pragma unroll
        for (int kk = 0; kk < 8; ++kk)
            p += aw[c*512 + kk*64 + lane] * wsv[kk*64 + lane];
        #pragma unroll
        for (int off = 32; off; off >>= 1) p += __shfl_down(p, off, 64);
        if (lane == 0) op[b*512 + c] = (p + ab[c]) * scale;
    }
}

// ---------------- P2: w2sum[o][c] = sum_t conv_w[o][c][t]^2 ;  Abf[t][o][c] = bf16(conv_w)
__global__ __launch_bounds__(256) void k_prepw(const float* __restrict__ conv_w,
                        float* __restrict__ w2sum, __hip_bfloat16* __restrict__ Abf) {
    int o = blockIdx.x, tid = threadIdx.x;
    __shared__ float wrow[4608];
    const f32x4* src = (const f32x4*)(conv_w + o*4608);
    #pragma unroll
    for (int r = 0; r < 5; ++r) {
        int idx = tid + (r << 8);
        if (idx < 1152) *(f32x4*)&wrow[idx*4] = src[idx];
    }
    __syncthreads();
    #pragma unroll
    for (int j = 0; j < 2; ++j) {
        int c = tid + (j << 8);
        float sum = 0.f;
        #pragma unroll
        for (int t = 0; t < 9; ++t) {
            float v = wrow[c*9 + t];
            sum += v*v;
            Abf[(t*512 + o)*512 + c] = __float2bfloat16(v);
        }
        w2sum[o*512 + c] = sum;
    }
}

// ---------------- P3: dcoef (1 wave per (b,o)) + rgbc[b][o3][c] on first 96 blocks
__global__ __launch_bounds__(256) void k_dcoef(const float* __restrict__ sbuf,
                                               const float* __restrict__ w2sum,
                                               const float* __restrict__ s2buf,
                                               const float* __restrict__ rgb_w,
                                               float* __restrict__ dcoef,
                                               float* __restrict__ rgbc) {
    int gw = blockIdx.x*4 + (threadIdx.x >> 6);
    int lane = threadIdx.x & 63;
    int b = gw >> 9, o = gw & 511;
    float acc = 0.f;
    #pragma unroll
    for (int i = 0; i < 8; ++i) {
        int c = (i << 6) + lane;
        float sv = sbuf[(b << 9) + c];
        acc += sv*sv*w2sum[(o << 9) + c];
    }
    #pragma unroll
    for (int off = 32; off; off >>= 1) acc += __shfl_down(acc, off, 64);
    if (lane == 0) dcoef[(b << 9) + o] = rsqrtf(acc + 1e-8f);
    if (blockIdx.x < 96) {
        int flat = blockIdx.x*256 + threadIdx.x;   // = b*1536 + o3*512 + c
        int bb = flat / 1536;
        int r  = flat - bb*1536;
        int c  = r & 511;
        rgbc[flat] = rgb_w[r] * s2buf[bb*512 + c];
    }
}

// ---------------- P4: Ypad[b][h+1][w+1][c] = bf16(s[b][c] * const[c][h][w])  (interior)
__global__ void k_ypad(const float* __restrict__ cst, const float* __restrict__ sbuf,
                       __hip_bfloat16* __restrict__ Ypad) {
    int b = blockIdx.x >> 6, h = blockIdx.x & 63, tid = threadIdx.x;
    __shared__ float tile[64][65];
    for (int cc = 0; cc < 8; ++cc) {
        int c0 = cc << 6;
        #pragma unroll
        for (int it = 0; it < 16; ++it) {
            int cl = (it << 2) + (tid >> 6);
            int w = tid & 63;
            tile[cl][w] = cst[(c0 + cl)*4096 + (h << 6) + w];
        }
        __syncthreads();
        #pragma unroll
        for (int it = 0; it < 16; ++it) {
            int flat = (it << 8) + tid;
            int w = flat >> 6, cl = flat & 63;
            float v = sbuf[(b << 9) + c0 + cl] * tile[cl][w];
            Ypad[(((b*66 + h + 1)*66) + (w + 1))*512 + c0 + cl] = __float2bfloat16(v);
        }
        __syncthreads();
    }
}

// ---------------- main conv GEMM: counted-vmcnt tap pipeline (T3+T4+T5)
// 144 uniform phases (16 c-chunks x 9 taps, 16 MFMA each). A: 4-slot tap ring,
// prefetch distance 3 phases. B-halo: double-buffered, next chunk staged 1
// round/phase over taps 0..4 (distance ~9..4 phases). One raw s_barrier per
// phase with counted vmcnt — never vmcnt(0) in the main loop. Dummy tail
// stages keep the vmcnt schedule uniform (writes land in rings/halves that
// are no longer read — verified safe).
__global__ __launch_bounds__(256, 2) void conv_gemm(
    const short* __restrict__ Abf,   // [9][512][512] bf16
    const short* __restrict__ Ypad,  // [16][66][66][512] bf16
    const float* __restrict__ dcoef, // [16][512]
    const float* __restrict__ noise, // [4096]
    const float* __restrict__ nstr,  // [1]
    const float* __restrict__ bias,  // [512]
    const float* __restrict__ rgbc,  // [16][3][512]
    float* __restrict__ xout,        // [16][512][4096]
    float* __restrict__ img)         // [16][3][4096], pre-init to rgb_b
{
    __shared__ short Aring[16384];    // 4 ring slots x [128 row][32 c], XOR-swizzled
    __shared__ short Bh2[16896];      // 2 halves x [264 pos][32 c], XOR-swizzled
    __shared__ float red[128][3][2];  // ToRGB partials [hwl][o3][m-half]
    int tid = threadIdx.x, lane = tid & 63, wv = tid >> 6;

    int blk = blockIdx.x;
    int xcd = blk & 7, idx = blk >> 3;
    int mblk = xcd & 3;
    int nblk = idx | ((xcd >> 2) << 8);
    int b  = nblk >> 5;
    int n0 = (nblk & 31) << 7;
    int o0 = mblk << 7;
    int h0 = n0 >> 6;                 // top of 4-row halo window in padded coords

    // B-halo staging offsets: rounds 0..3 (256 slots each) + remainder (32 slots)
    int bgofs[4];
    #pragma unroll
    for (int r = 0; r < 4; ++r) {
        int i = tid + (r << 8);
        int p = i >> 2;
        int hl = p / 66;
        int w  = p - hl*66;
        int q  = (i & 3) ^ ((p >> 1) & 3);
        bgofs[r] = (((b*66 + h0 + hl)*66) + w)*512 + q*8;
    }
    int i4 = 1024 + (lane & 31);      // remainder slots 1024..1055 (lane<32 of EVERY wave)
    int p4 = i4 >> 2;
    int hl4 = p4 / 66;
    int w4 = p4 - hl4*66;
    int q4 = (i4 & 3) ^ ((p4 >> 1) & 3);
    int bgofs4 = (((b*66 + h0 + hl4)*66) + w4)*512 + q4*8;

    // A staging offsets: slot = tid + 256r  (512 slots = 1 tap of 128 rows x 32 c)
    int aofs[2];
    #pragma unroll
    for (int r = 0; r < 2; ++r) {
        int s = tid + (r << 8);
        int row = s >> 2;
        int q = (s & 3) ^ ((row >> 1) & 3);
        aofs[r] = ((o0 + row) << 9) + q*8;
    }

    int quad = lane >> 4, ml = lane & 15;
    int sa = (quad ^ ((ml >> 1) & 3)) << 3;
    int mw = (wv & 1) << 6, nw = (wv >> 1) << 6;
    int nh = nw >> 6;
    short* BW0 = Bh2 + ((tid & ~63) << 3);   // wave-uniform B dest base (half 0)
    short* AW0 = Aring + (wv << 9);          // wave-uniform A dest base (+ring*4096+r*2048)

    f32x4 acc[4][4] = {};

    // ---- prologue: B chunk0 -> half0 (5 instrs), then A taps 0..2 -> rings 0..2 (6)
    #pragma unroll
    for (int r = 0; r < 4; ++r) glds16(Ypad + bgofs[r], BW0 + (r << 11));
    if (lane < 32) glds16(Ypad + bgofs4, Bh2 + 8192);
    #pragma unroll
    for (int t = 0; t < 3; ++t) {
        glds16(Abf + (t << 18) + aofs[0], AW0 + t*4096);
        glds16(Abf + (t << 18) + aofs[1], AW0 + t*4096 + 2048);
    }
    // need B + A(ring0) complete; A(ring1), A(ring2) may stay in flight
    asm volatile("s_waitcnt vmcnt(4)" ::: "memory");
    __builtin_amdgcn_s_barrier();

    for (int ch = 0; ch < 16; ++ch) {
        int c0 = ch << 5;
        int half = ch & 1;
        const short* Bbase = Bh2 + (half ? 8448 : 0);
        short* BWn  = Bh2 + (half ? 0 : 8448) + ((tid & ~63) << 3);
        short* Brem = Bh2 + (half ? 0 : 8448) + 8192;
        int c0n = (c0 + 32) & 511;    // wraps to 0 on last chunk (dummy, garbage-safe)
        int rb = ch & 3;              // 9*ch mod 4 == ch mod 4
        #pragma unroll
        for (int tap = 0; tap < 9; ++tap) {
            int rr = (rb + tap) & 3;          // ring read this phase
            int rw = (rb + tap + 3) & 3;      // ring written for phase T+3
            int tapP = (tap < 6) ? tap + 3 : tap - 6;
            int c0P  = (tap < 6) ? c0 : c0n;
            // A prefetch for phase T+3 (2 instrs, every phase incl. tail dummies)
            const short* asrc = Abf + (tapP << 18) + c0P;
            glds16(asrc + aofs[0], AW0 + rw*4096);
            glds16(asrc + aofs[1], AW0 + rw*4096 + 2048);
            // B prefetch for next chunk: 1 round per phase on taps 0..4
            if (tap < 4)
                glds16(Ypad + bgofs[tap] + c0n, BWn + (tap << 11));
            if (tap == 4) {
                if (lane < 32) glds16(Ypad + bgofs4 + c0n, Brem);
            }
            // compute: tap = dh*3 + tl
            int dh = tap / 3, tl = tap % 3;
            const short* Ar = Aring + rr*4096;
            int pb = (nh + dh)*66 + ml + tl;
            int swz = (quad ^ ((pb >> 1) & 3)) << 3;
            short8 af[4], bf[4];
            #pragma unroll
            for (int i = 0; i < 4; ++i) {
                af[i] = *(const short8*)(Ar + (mw + ml + i*16)*32 + sa);
                bf[i] = *(const short8*)(Bbase + (pb + i*16)*32 + swz);
            }
            __builtin_amdgcn_s_setprio(1);
            #pragma unroll
            for (int mi = 0; mi < 4; ++mi)
                #pragma unroll
                for (int ni = 0; ni < 4; ++ni)
                    acc[mi][ni] = __builtin_amdgcn_mfma_f32_16x16x32_bf16(af[mi], bf[ni], acc[mi][ni], 0, 0, 0);
            __builtin_amdgcn_s_setprio(0);
            // counted waits (per-wave in-flight accounting; see analysis):
            // ensure ring for phase T+1 (staged at T-2) + aged-out B rounds complete.
            {
                constexpr int VM[9] = {5, 6, 7, 7, 7, 6, 5, 4, 4};
                asm volatile("s_waitcnt vmcnt(%0)" :: "i"(VM[tap]) : "memory");
            }
            __builtin_amdgcn_s_barrier();
        }
    }

    // ---------------- epilogue: demod + noise + bias + lrelu + store + fused ToRGB
    float ns = nstr[0];
    float pr[4][3] = {};
    #pragma unroll
    for (int mi = 0; mi < 4; ++mi) {
        int ob = o0 + mw + mi*16 + (quad << 2);
        f32x4 dc  = *(const f32x4*)(dcoef + (b << 9) + ob);
        f32x4 bs4 = *(const f32x4*)(bias + ob);
        f32x4 rc0 = *(const f32x4*)(rgbc + b*1536 + ob);
        f32x4 rc1 = *(const f32x4*)(rgbc + b*1536 + 512 + ob);
        f32x4 rc2 = *(const f32x4*)(rgbc + b*1536 + 1024 + ob);
        #pragma unroll
        for (int ni = 0; ni < 4; ++ni) {
            int hw = n0 + nw + ni*16 + ml;
            float nz = noise[hw] * ns;
            #pragma unroll
            for (int r = 0; r < 4; ++r) {
                float v = acc[mi][ni][r] * dc[r] + nz + bs4[r];
                v = (v < 0.0f ? LRELU_SLOPE * v : v) * ACT_GAIN;
                xout[(((b << 9) + ob + r) << 12) + hw] = v;
                pr[ni][0] += v * rc0[r];
                pr[ni][1] += v * rc1[r];
                pr[ni][2] += v * rc2[r];
            }
        }
    }
    #pragma unroll
    for (int ni = 0; ni < 4; ++ni)
        #pragma unroll
        for (int o3 = 0; o3 < 3; ++o3) {
            float v = pr[ni][o3];
            v += __shfl_down(v, 16, 64);
            v += __shfl_down(v, 32, 64);
            pr[ni][o3] = v;
        }
    if (lane < 16) {
        #pragma unroll
        for (int ni = 0; ni < 4; ++ni)
            #pragma unroll
            for (int o3 = 0; o3 < 3; ++o3)
                red[nw + ni*16 + ml][o3][wv & 1] = pr[ni][o3];
    }
    __syncthreads();
    // 384 (o3,hwl) pairs, 256 threads: strided loop
    for (int p = tid; p < 384; p += 256) {
        int o3 = p >> 7, hwl = p & 127;
        float v = red[hwl][o3][0] + red[hwl][o3][1];
        atomicAdd(img + ((b*3 + o3) << 12) + n0 + hwl, v);
    }
}

extern "C" void kernel_launch(void* const* d_in, const int* in_sizes, int n_in,
                              void* d_out, int out_size, void* d_ws, size_t ws_size,
                              hipStream_t stream) {
    (void)in_sizes; (void)n_in; (void)out_size; (void)ws_size;
    const float* wsin   = (const float*)d_in[0];   // [16][2][512]
    const float* cst    = (const float*)d_in[1];   // [512][64][64]
    const float* conv_w = (const float*)d_in[2];   // [512][512][3][3]
    const float* conv_b = (const float*)d_in[3];   // [512]
    const float* caw    = (const float*)d_in[4];   // [512][512]
    const float* cab    = (const float*)d_in[5];   // [512]
    const float* noise  = (const float*)d_in[6];   // [64][64]
    const float* nstr   = (const float*)d_in[7];   // [1]
    const float* rgb_w  = (const float*)d_in[8];   // [3][512][1][1]
    const float* rgb_b  = (const float*)d_in[9];   // [3]
    const float* raw_   = (const float*)d_in[10];  // [512][512]
    const float* rab    = (const float*)d_in[11];  // [512]

    char* wsb = (char*)d_ws;
    float* sbuf   = (float*)(wsb + 0);         // 16*512 f32
    float* s2buf  = (float*)(wsb + 32768);     // 16*512 f32
    float* dcoef  = (float*)(wsb + 65536);     // 16*512 f32
    float* rgbc   = (float*)(wsb + 98304);     // 16*3*512 f32
    float* w2sum  = (float*)(wsb + 196608);    // 512*512 f32 ([o][c])
    __hip_bfloat16* Abf  = (__hip_bfloat16*)(wsb + 1245184);  // 9*512*512 bf16
    __hip_bfloat16* Ypad = (__hip_bfloat16*)(wsb + 5963776);  // 16*66*66*512 bf16

    float* xout = (float*)d_out;               // [16][512][4096]
    float* img  = xout + 33554432;             // [16][3][4096]

    k_init<<<1088, 256, 0, stream>>>(Ypad, rgb_b, img);
    k_styles<<<dim3(16, 2), 256, 0, stream>>>(wsin, caw, cab, raw_, rab, sbuf, s2buf);
    k_prepw<<<512, 256, 0, stream>>>(conv_w, w2sum, Abf);
    k_dcoef<<<2048, 256, 0, stream>>>(sbuf, w2sum, s2buf, rgb_w, dcoef, rgbc);
    k_ypad<<<1024, 256, 0, stream>>>(cst, sbuf, Ypad);
    conv_gemm<<<2048, 256, 0, stream>>>((const short*)Abf, (const short*)Ypad,
                                        dcoef, noise, nstr, conv_b, rgbc, xout, img);
}

// Round 2
// 593.200 us; speedup vs baseline: 1.0925x; 1.0925x over previous
//
#include <hip/hip_runtime.h>
#include <hip/hip_bf16.h>

typedef __attribute__((ext_vector_type(8))) short short8;
typedef __attribute__((ext_vector_type(4))) float f32x4;

#define LRELU_SLOPE 0.2f
#define ACT_GAIN 1.41421356237309515f
#define WG_RGB 0.04419417382415922f   // 1/sqrt(512)

__device__ __forceinline__ void glds16(const short* g, short* l) {
    __builtin_amdgcn_global_load_lds(
        (const __attribute__((address_space(1))) unsigned int*)g,
        (__attribute__((address_space(3))) unsigned int*)l, 16, 0, 0);
}

// ---------------- P0: zero Ypad border + init img to rgb_b
__global__ void k_init(__hip_bfloat16* __restrict__ Ypad,
                       const float* __restrict__ rgb_b, float* __restrict__ img) {
    int blk = blockIdx.x, tid = threadIdx.x;
    if (blk < 1040) {                       // border: 4160 slots, 4 per block
        int gslot = blk*4 + (tid >> 6);
        int b = gslot / 260;
        int cell = gslot - b*260;
        int h, w;
        if (cell < 66)       { h = 0;          w = cell; }
        else if (cell < 132) { h = 65;         w = cell - 66; }
        else if (cell < 196) { h = cell - 131; w = 0; }
        else                 { h = cell - 195; w = 65; }
        short8 z = {};
        *(short8*)((short*)Ypad + (((b*66 + h)*66) + w)*512 + (tid & 63)*8) = z;
    } else {                                // img init: 48 blocks x 4 f32x4 (49152 f32x4 total)
        int blk2 = blk - 1040;
        #pragma unroll
        for (int j = 0; j < 4; ++j) {
            int f4 = blk2*1024 + j*256 + tid;   // 0..49151 (f32x4 units)
            int b3 = f4 >> 10;                  // plane = 1024 f32x4
            int o3 = b3 % 3;
            float v = rgb_b[o3];
            f32x4 vv = {v, v, v, v};
            *(f32x4*)(img + f4*4) = vv;
        }
    }
}

// ---------------- P1: styles  s = ws[:,0]@caw^T + cab ;  s2 = (ws[:,1]@raw^T + rab)*wg
__global__ void k_styles(const float* __restrict__ wsin,
                         const float* __restrict__ caw, const float* __restrict__ cab,
                         const float* __restrict__ raw_, const float* __restrict__ rab,
                         float* __restrict__ sbuf, float* __restrict__ s2buf) {
    int b = blockIdx.x, which = blockIdx.y;
    int tid = threadIdx.x, lane = tid & 63, wv = tid >> 6;
    const float* aw = which ? raw_ : caw;
    const float* ab = which ? rab : cab;
    float scale = which ? WG_RGB : 1.0f;
    float* op = which ? s2buf : sbuf;
    __shared__ float wsv[512];
    wsv[tid]       = wsin[(b*2 + which)*512 + tid];
    wsv[tid + 256] = wsin[(b*2 + which)*512 + tid + 256];
    __syncthreads();
    for (int c = wv; c < 512; c += 4) {
        float p = 0.f;
        #pragma unroll
        for (int kk = 0; kk < 8; ++kk)
            p += aw[c*512 + kk*64 + lane] * wsv[kk*64 + lane];
        #pragma unroll
        for (int off = 32; off; off >>= 1) p += __shfl_down(p, off, 64);
        if (lane == 0) op[b*512 + c] = (p + ab[c]) * scale;
    }
}

// ---------------- P2: w2sum[o][c] = sum_t conv_w[o][c][t]^2 ;  Abf[t][o][c] = bf16(conv_w)
__global__ __launch_bounds__(256) void k_prepw(const float* __restrict__ conv_w,
                        float* __restrict__ w2sum, __hip_bfloat16* __restrict__ Abf) {
    int o = blockIdx.x, tid = threadIdx.x;
    __shared__ float wrow[4608];
    const f32x4* src = (const f32x4*)(conv_w + o*4608);
    #pragma unroll
    for (int r = 0; r < 5; ++r) {
        int idx = tid + (r << 8);
        if (idx < 1152) *(f32x4*)&wrow[idx*4] = src[idx];
    }
    __syncthreads();
    #pragma unroll
    for (int j = 0; j < 2; ++j) {
        int c = tid + (j << 8);
        float sum = 0.f;
        #pragma unroll
        for (int t = 0; t < 9; ++t) {
            float v = wrow[c*9 + t];
            sum += v*v;
            Abf[(t*512 + o)*512 + c] = __float2bfloat16(v);
        }
        w2sum[o*512 + c] = sum;
    }
}

// ---------------- P3: dcoef (1 wave per (b,o)) + rgbc[b][o3][c] on first 96 blocks
__global__ __launch_bounds__(256) void k_dcoef(const float* __restrict__ sbuf,
                                               const float* __restrict__ w2sum,
                                               const float* __restrict__ s2buf,
                                               const float* __restrict__ rgb_w,
                                               float* __restrict__ dcoef,
                                               float* __restrict__ rgbc) {
    int gw = blockIdx.x*4 + (threadIdx.x >> 6);
    int lane = threadIdx.x & 63;
    int b = gw >> 9, o = gw & 511;
    float acc = 0.f;
    #pragma unroll
    for (int i = 0; i < 8; ++i) {
        int c = (i << 6) + lane;
        float sv = sbuf[(b << 9) + c];
        acc += sv*sv*w2sum[(o << 9) + c];
    }
    #pragma unroll
    for (int off = 32; off; off >>= 1) acc += __shfl_down(acc, off, 64);
    if (lane == 0) dcoef[(b << 9) + o] = rsqrtf(acc + 1e-8f);
    if (blockIdx.x < 96) {
        int flat = blockIdx.x*256 + threadIdx.x;   // = b*1536 + o3*512 + c
        int bb = flat / 1536;
        int r  = flat - bb*1536;
        int c  = r & 511;
        rgbc[flat] = rgb_w[r] * s2buf[bb*512 + c];
    }
}

// ---------------- P4: Ypad[b][h+1][w+1][c] = bf16(s[b][c] * const[c][h][w])  (interior)
__global__ void k_ypad(const float* __restrict__ cst, const float* __restrict__ sbuf,
                       __hip_bfloat16* __restrict__ Ypad) {
    int b = blockIdx.x >> 6, h = blockIdx.x & 63, tid = threadIdx.x;
    __shared__ float tile[64][65];
    for (int cc = 0; cc < 8; ++cc) {
        int c0 = cc << 6;
        #pragma unroll
        for (int it = 0; it < 16; ++it) {
            int cl = (it << 2) + (tid >> 6);
            int w = tid & 63;
            tile[cl][w] = cst[(c0 + cl)*4096 + (h << 6) + w];
        }
        __syncthreads();
        #pragma unroll
        for (int it = 0; it < 16; ++it) {
            int flat = (it << 8) + tid;
            int w = flat >> 6, cl = flat & 63;
            float v = sbuf[(b << 9) + c0 + cl] * tile[cl][w];
            Ypad[(((b*66 + h + 1)*66) + (w + 1))*512 + c0 + cl] = __float2bfloat16(v);
        }
        __syncthreads();
    }
}

// ---------------- main conv GEMM: counted-vmcnt tap pipeline + REGISTER
// double-buffered fragments. Phase T issues ds_reads for phase T+1's frags
// BEFORE the MFMA cluster of phase T (which consumes regs loaded at T-1),
// so LDS latency/BW hides under the ~310cy MFMA issue shadow. vmcnt ledger
// shifted one phase earlier (slot T+2 complete at end of T): VMP below.
__global__ __launch_bounds__(256, 2) void conv_gemm(
    const short* __restrict__ Abf,   // [9][512][512] bf16
    const short* __restrict__ Ypad,  // [16][66][66][512] bf16
    const float* __restrict__ dcoef, // [16][512]
    const float* __restrict__ noise, // [4096]
    const float* __restrict__ nstr,  // [1]
    const float* __restrict__ bias,  // [512]
    const float* __restrict__ rgbc,  // [16][3][512]
    float* __restrict__ xout,        // [16][512][4096]
    float* __restrict__ img)         // [16][3][4096], pre-init to rgb_b
{
    __shared__ short Aring[16384];    // 4 ring slots x [128 row][32 c], XOR-swizzled
    __shared__ short Bh2[16896];      // 2 halves x [264 pos][32 c], XOR-swizzled
    __shared__ float red[128][3][2];  // ToRGB partials [hwl][o3][m-half]
    int tid = threadIdx.x, lane = tid & 63, wv = tid >> 6;

    int blk = blockIdx.x;
    int xcd = blk & 7, idx = blk >> 3;
    int mblk = xcd & 3;
    int nblk = idx | ((xcd >> 2) << 8);
    int b  = nblk >> 5;
    int n0 = (nblk & 31) << 7;
    int o0 = mblk << 7;
    int h0 = n0 >> 6;                 // top of 4-row halo window in padded coords

    // B-halo staging offsets: rounds 0..3 (256 slots each) + remainder (32 slots)
    int bgofs[4];
    #pragma unroll
    for (int r = 0; r < 4; ++r) {
        int i = tid + (r << 8);
        int p = i >> 2;
        int hl = p / 66;
        int w  = p - hl*66;
        int q  = (i & 3) ^ ((p >> 1) & 3);
        bgofs[r] = (((b*66 + h0 + hl)*66) + w)*512 + q*8;
    }
    int i4 = 1024 + (lane & 31);      // remainder slots 1024..1055 (lane<32 of EVERY wave)
    int p4 = i4 >> 2;
    int hl4 = p4 / 66;
    int w4 = p4 - hl4*66;
    int q4 = (i4 & 3) ^ ((p4 >> 1) & 3);
    int bgofs4 = (((b*66 + h0 + hl4)*66) + w4)*512 + q4*8;

    // A staging offsets: slot = tid + 256r  (512 slots = 1 tap of 128 rows x 32 c)
    int aofs0, aofs1;
    {
        int s0 = tid,       r0 = s0 >> 2, q0 = (s0 & 3) ^ ((r0 >> 1) & 3);
        int s1 = tid + 256, r1 = s1 >> 2, q1 = (s1 & 3) ^ ((r1 >> 1) & 3);
        aofs0 = ((o0 + r0) << 9) + q0*8;
        aofs1 = ((o0 + r1) << 9) + q1*8;
    }

    int quad = lane >> 4, ml = lane & 15;
    int sa = (quad ^ ((ml >> 1) & 3)) << 3;
    int mw = (wv & 1) << 6, nw = (wv >> 1) << 6;
    int nh = nw >> 6;
    const short* H0 = Bh2;                    // half 0 read base
    const short* H1 = Bh2 + 8448;             // half 1 read base
    short* BW0h = Bh2 + ((tid & ~63) << 3);   // wave-uniform write base, half 0
    short* BW1h = BW0h + 8448;                // wave-uniform write base, half 1
    short* Brem0 = Bh2 + 8192;                // remainder region, half 0
    short* Brem1 = Bh2 + 8448 + 8192;         // remainder region, half 1
    short* AW0 = Aring + (wv << 9);           // wave-uniform A write base

    f32x4 acc[4][4] = {};
    short8 fa[2][4], fb[2][4];                // reg double-buffered fragments

    // ---- prologue: B chunk0 -> half0 (5 instrs), A taps 0..2 -> rings 0..2 (6)
    #pragma unroll
    for (int r = 0; r < 4; ++r) glds16(Ypad + bgofs[r], BW0h + (r << 11));
    if (lane < 32) glds16(Ypad + bgofs4, Brem0);
    #pragma unroll
    for (int t = 0; t < 3; ++t) {
        glds16(Abf + (t << 18) + aofs0, AW0 + t*4096);
        glds16(Abf + (t << 18) + aofs1, AW0 + t*4096 + 2048);
    }
    // drain B + ring0 + ring1 (read-ahead during phase (0,0) touches ring1);
    // ring2's 2 loads stay in flight.
    asm volatile("s_waitcnt vmcnt(2)" ::: "memory");
    __builtin_amdgcn_s_barrier();
    // preload frags for phase (0,0): ring0, half0, tap0
    {
        int pb0 = nh*66 + ml;
        int swz0 = (quad ^ ((pb0 >> 1) & 3)) << 3;
        #pragma unroll
        for (int i = 0; i < 4; ++i) {
            fa[0][i] = *(const short8*)(Aring + (mw + ml + i*16)*32 + sa);
            fb[0][i] = *(const short8*)(H0 + (pb0 + i*16)*32 + swz0);
        }
    }

    // vmcnt ledger (per-wave, A=2/phase + B on taps 0..4; guarantee: at end of
    // phase T, A-slot for T+2 done; all next-chunk B done by end of (ch,7)).
    constexpr int VMP[9] = {3, 4, 4, 4, 4, 3, 2, 2, 2};

#define PHASE(TAP, CUR, C0, C0N, RB, BC, BN, BWN, BRM)                          \
    {                                                                           \
        constexpr int TAPN = ((TAP) + 1) % 9;                                   \
        constexpr int NXT = (CUR) ^ 1;                                          \
        /* read-ahead: frags for phase T+1 */                                   \
        int rrN = ((RB) + (TAP) + 1) & 3;                                       \
        const short* ArN = Aring + rrN*4096;                                    \
        const short* BbN = ((TAP) == 8) ? (BN) : (BC);                          \
        int pbN = (nh + TAPN/3)*66 + ml + TAPN%3;                               \
        int swzN = (quad ^ ((pbN >> 1) & 3)) << 3;                              \
        _Pragma("unroll")                                                       \
        for (int i = 0; i < 4; ++i) {                                           \
            fa[NXT][i] = *(const short8*)(ArN + (mw + ml + i*16)*32 + sa);      \
            fb[NXT][i] = *(const short8*)(BbN + (pbN + i*16)*32 + swzN);        \
        }                                                                       \
        /* glds prefetch: A for phase T+3 (A,A then B — ledger order) */        \
        {                                                                       \
            constexpr int TAPP = ((TAP) < 6) ? (TAP) + 3 : (TAP) - 6;           \
            const short* asrc = Abf + (TAPP << 18) + (((TAP) < 6) ? (C0) : (C0N)); \
            int rw = ((RB) + (TAP) + 3) & 3;                                    \
            glds16(asrc + aofs0, AW0 + rw*4096);                                \
            glds16(asrc + aofs1, AW0 + rw*4096 + 2048);                         \
        }                                                                       \
        if ((TAP) < 4) glds16(Ypad + bgofs[(TAP)] + (C0N), (BWN) + ((TAP) << 11)); \
        if ((TAP) == 4) { if (lane < 32) glds16(Ypad + bgofs4 + (C0N), (BRM)); } \
        __builtin_amdgcn_sched_barrier(0);                                      \
        __builtin_amdgcn_s_setprio(1);                                          \
        _Pragma("unroll")                                                       \
        for (int mi = 0; mi < 4; ++mi)                                          \
            _Pragma("unroll")                                                   \
            for (int ni = 0; ni < 4; ++ni)                                      \
                acc[mi][ni] = __builtin_amdgcn_mfma_f32_16x16x32_bf16(          \
                    fa[(CUR)][mi], fb[(CUR)][ni], acc[mi][ni], 0, 0, 0);        \
        __builtin_amdgcn_s_setprio(0);                                          \
        asm volatile("s_waitcnt vmcnt(%0)" :: "i"(VMP[(TAP)]) : "memory");      \
        __builtin_amdgcn_s_barrier();                                           \
    }

#define CHUNK9(PAR, C0, C0N, RB, BC, BN, BWN, BRM)                              \
    PHASE(0, ((0 + (PAR)) & 1), C0, C0N, RB, BC, BN, BWN, BRM)                  \
    PHASE(1, ((1 + (PAR)) & 1), C0, C0N, RB, BC, BN, BWN, BRM)                  \
    PHASE(2, ((2 + (PAR)) & 1), C0, C0N, RB, BC, BN, BWN, BRM)                  \
    PHASE(3, ((3 + (PAR)) & 1), C0, C0N, RB, BC, BN, BWN, BRM)                  \
    PHASE(4, ((4 + (PAR)) & 1), C0, C0N, RB, BC, BN, BWN, BRM)                  \
    PHASE(5, ((5 + (PAR)) & 1), C0, C0N, RB, BC, BN, BWN, BRM)                  \
    PHASE(6, ((6 + (PAR)) & 1), C0, C0N, RB, BC, BN, BWN, BRM)                  \
    PHASE(7, ((7 + (PAR)) & 1), C0, C0N, RB, BC, BN, BWN, BRM)                  \
    PHASE(8, ((8 + (PAR)) & 1), C0, C0N, RB, BC, BN, BWN, BRM)

    // chunk-pair loop: even chunk (half0, parity 0), odd chunk (half1, parity 1)
    for (int cc = 0; cc < 8; ++cc) {
        int c0e = cc << 6;                // even chunk ch=2cc
        int rbe = (cc << 1) & 3;
        CHUNK9(0, c0e, c0e + 32, rbe, H0, H1, BW1h, Brem1)
        int c0o = c0e + 32;               // odd chunk ch=2cc+1
        int c0no = (c0e + 64) & 511;      // wraps to 0 on last chunk (dummy)
        int rbo = (rbe + 1) & 3;
        CHUNK9(1, c0o, c0no, rbo, H1, H0, BW0h, Brem0)
    }
#undef PHASE
#undef CHUNK9

    // ---------------- epilogue: demod + noise + bias + lrelu + store + fused ToRGB
    float ns = nstr[0];
    float pr[4][3] = {};
    #pragma unroll
    for (int mi = 0; mi < 4; ++mi) {
        int ob = o0 + mw + mi*16 + (quad << 2);
        f32x4 dc  = *(const f32x4*)(dcoef + (b << 9) + ob);
        f32x4 bs4 = *(const f32x4*)(bias + ob);
        f32x4 rc0 = *(const f32x4*)(rgbc + b*1536 + ob);
        f32x4 rc1 = *(const f32x4*)(rgbc + b*1536 + 512 + ob);
        f32x4 rc2 = *(const f32x4*)(rgbc + b*1536 + 1024 + ob);
        #pragma unroll
        for (int ni = 0; ni < 4; ++ni) {
            int hw = n0 + nw + ni*16 + ml;
            float nz = noise[hw] * ns;
            #pragma unroll
            for (int r = 0; r < 4; ++r) {
                float v = acc[mi][ni][r] * dc[r] + nz + bs4[r];
                v = (v < 0.0f ? LRELU_SLOPE * v : v) * ACT_GAIN;
                xout[(((b << 9) + ob + r) << 12) + hw] = v;
                pr[ni][0] += v * rc0[r];
                pr[ni][1] += v * rc1[r];
                pr[ni][2] += v * rc2[r];
            }
        }
    }
    #pragma unroll
    for (int ni = 0; ni < 4; ++ni)
        #pragma unroll
        for (int o3 = 0; o3 < 3; ++o3) {
            float v = pr[ni][o3];
            v += __shfl_down(v, 16, 64);
            v += __shfl_down(v, 32, 64);
            pr[ni][o3] = v;
        }
    if (lane < 16) {
        #pragma unroll
        for (int ni = 0; ni < 4; ++ni)
            #pragma unroll
            for (int o3 = 0; o3 < 3; ++o3)
                red[nw + ni*16 + ml][o3][wv & 1] = pr[ni][o3];
    }
    __syncthreads();
    // 384 (o3,hwl) pairs, 256 threads: strided loop
    for (int p = tid; p < 384; p += 256) {
        int o3 = p >> 7, hwl = p & 127;
        float v = red[hwl][o3][0] + red[hwl][o3][1];
        atomicAdd(img + ((b*3 + o3) << 12) + n0 + hwl, v);
    }
}

extern "C" void kernel_launch(void* const* d_in, const int* in_sizes, int n_in,
                              void* d_out, int out_size, void* d_ws, size_t ws_size,
                              hipStream_t stream) {
    (void)in_sizes; (void)n_in; (void)out_size; (void)ws_size;
    const float* wsin   = (const float*)d_in[0];   // [16][2][512]
    const float* cst    = (const float*)d_in[1];   // [512][64][64]
    const float* conv_w = (const float*)d_in[2];   // [512][512][3][3]
    const float* conv_b = (const float*)d_in[3];   // [512]
    const float* caw    = (const float*)d_in[4];   // [512][512]
    const float* cab    = (const float*)d_in[5];   // [512]
    const float* noise  = (const float*)d_in[6];   // [64][64]
    const float* nstr   = (const float*)d_in[7];   // [1]
    const float* rgb_w  = (const float*)d_in[8];   // [3][512][1][1]
    const float* rgb_b  = (const float*)d_in[9];   // [3]
    const float* raw_   = (const float*)d_in[10];  // [512][512]
    const float* rab    = (const float*)d_in[11];  // [512]

    char* wsb = (char*)d_ws;
    float* sbuf   = (float*)(wsb + 0);         // 16*512 f32
    float* s2buf  = (float*)(wsb + 32768);     // 16*512 f32
    float* dcoef  = (float*)(wsb + 65536);     // 16*512 f32
    float* rgbc   = (float*)(wsb + 98304);     // 16*3*512 f32
    float* w2sum  = (float*)(wsb + 196608);    // 512*512 f32 ([o][c])
    __hip_bfloat16* Abf  = (__hip_bfloat16*)(wsb + 1245184);  // 9*512*512 bf16
    __hip_bfloat16* Ypad = (__hip_bfloat16*)(wsb + 5963776);  // 16*66*66*512 bf16

    float* xout = (float*)d_out;               // [16][512][4096]
    float* img  = xout + 33554432;             // [16][3][4096]

    k_init<<<1088, 256, 0, stream>>>(Ypad, rgb_b, img);
    k_styles<<<dim3(16, 2), 256, 0, stream>>>(wsin, caw, cab, raw_, rab, sbuf, s2buf);
    k_prepw<<<512, 256, 0, stream>>>(conv_w, w2sum, Abf);
    k_dcoef<<<2048, 256, 0, stream>>>(sbuf, w2sum, s2buf, rgb_w, dcoef, rgbc);
    k_ypad<<<1024, 256, 0, stream>>>(cst, sbuf, Ypad);
    conv_gemm<<<2048, 256, 0, stream>>>((const short*)Abf, (const short*)Ypad,
                                        dcoef, noise, nstr, conv_b, rgbc, xout, img);
}

// Round 3
// 574.284 us; speedup vs baseline: 1.1285x; 1.0329x over previous
//
#include <hip/hip_runtime.h>
#include <hip/hip_bf16.h>

typedef __attribute__((ext_vector_type(8))) short short8;
typedef __attribute__((ext_vector_type(4))) float f32x4;
typedef __attribute__((ext_vector_type(16))) float f32x16;

#define LRELU_SLOPE 0.2f
#define ACT_GAIN 1.41421356237309515f
#define WG_RGB 0.04419417382415922f   // 1/sqrt(512)

__device__ __forceinline__ void glds16(const short* g, short* l) {
    __builtin_amdgcn_global_load_lds(
        (const __attribute__((address_space(1))) unsigned int*)g,
        (__attribute__((address_space(3))) unsigned int*)l, 16, 0, 0);
}

// ---------------- P0: zero Ypad border + init img to rgb_b
__global__ void k_init(__hip_bfloat16* __restrict__ Ypad,
                       const float* __restrict__ rgb_b, float* __restrict__ img) {
    int blk = blockIdx.x, tid = threadIdx.x;
    if (blk < 1040) {                       // border: 4160 slots, 4 per block
        int gslot = blk*4 + (tid >> 6);
        int b = gslot / 260;
        int cell = gslot - b*260;
        int h, w;
        if (cell < 66)       { h = 0;          w = cell; }
        else if (cell < 132) { h = 65;         w = cell - 66; }
        else if (cell < 196) { h = cell - 131; w = 0; }
        else                 { h = cell - 195; w = 65; }
        short8 z = {};
        *(short8*)((short*)Ypad + (((b*66 + h)*66) + w)*512 + (tid & 63)*8) = z;
    } else {                                // img init: 48 blocks x 4 f32x4 (49152 f32x4 total)
        int blk2 = blk - 1040;
        #pragma unroll
        for (int j = 0; j < 4; ++j) {
            int f4 = blk2*1024 + j*256 + tid;   // 0..49151 (f32x4 units)
            int b3 = f4 >> 10;                  // plane = 1024 f32x4
            int o3 = b3 % 3;
            float v = rgb_b[o3];
            f32x4 vv = {v, v, v, v};
            *(f32x4*)(img + f4*4) = vv;
        }
    }
}

// ---------------- P1: styles  s = ws[:,0]@caw^T + cab ;  s2 = (ws[:,1]@raw^T + rab)*wg
__global__ void k_styles(const float* __restrict__ wsin,
                         const float* __restrict__ caw, const float* __restrict__ cab,
                         const float* __restrict__ raw_, const float* __restrict__ rab,
                         float* __restrict__ sbuf, float* __restrict__ s2buf) {
    int b = blockIdx.x, which = blockIdx.y;
    int tid = threadIdx.x, lane = tid & 63, wv = tid >> 6;
    const float* aw = which ? raw_ : caw;
    const float* ab = which ? rab : cab;
    float scale = which ? WG_RGB : 1.0f;
    float* op = which ? s2buf : sbuf;
    __shared__ float wsv[512];
    wsv[tid]       = wsin[(b*2 + which)*512 + tid];
    wsv[tid + 256] = wsin[(b*2 + which)*512 + tid + 256];
    __syncthreads();
    for (int c = wv; c < 512; c += 4) {
        float p = 0.f;
        #pragma unroll
        for (int kk = 0; kk < 8; ++kk)
            p += aw[c*512 + kk*64 + lane] * wsv[kk*64 + lane];
        #pragma unroll
        for (int off = 32; off; off >>= 1) p += __shfl_down(p, off, 64);
        if (lane == 0) op[b*512 + c] = (p + ab[c]) * scale;
    }
}

// ---------------- P2: w2sum[o][c] = sum_t conv_w[o][c][t]^2 ;  Abf[t][o][c] = bf16(conv_w)
__global__ __launch_bounds__(256) void k_prepw(const float* __restrict__ conv_w,
                        float* __restrict__ w2sum, __hip_bfloat16* __restrict__ Abf) {
    int o = blockIdx.x, tid = threadIdx.x;
    __shared__ float wrow[4608];
    const f32x4* src = (const f32x4*)(conv_w + o*4608);
    #pragma unroll
    for (int r = 0; r < 5; ++r) {
        int idx = tid + (r << 8);
        if (idx < 1152) *(f32x4*)&wrow[idx*4] = src[idx];
    }
    __syncthreads();
    #pragma unroll
    for (int j = 0; j < 2; ++j) {
        int c = tid + (j << 8);
        float sum = 0.f;
        #pragma unroll
        for (int t = 0; t < 9; ++t) {
            float v = wrow[c*9 + t];
            sum += v*v;
            Abf[(t*512 + o)*512 + c] = __float2bfloat16(v);
        }
        w2sum[o*512 + c] = sum;
    }
}

// ---------------- P3: dcoef (1 wave per (b,o)) + rgbc[b][o3][c] on first 96 blocks
__global__ __launch_bounds__(256) void k_dcoef(const float* __restrict__ sbuf,
                                               const float* __restrict__ w2sum,
                                               const float* __restrict__ s2buf,
                                               const float* __restrict__ rgb_w,
                                               float* __restrict__ dcoef,
                                               float* __restrict__ rgbc) {
    int gw = blockIdx.x*4 + (threadIdx.x >> 6);
    int lane = threadIdx.x & 63;
    int b = gw >> 9, o = gw & 511;
    float acc = 0.f;
    #pragma unroll
    for (int i = 0; i < 8; ++i) {
        int c = (i << 6) + lane;
        float sv = sbuf[(b << 9) + c];
        acc += sv*sv*w2sum[(o << 9) + c];
    }
    #pragma unroll
    for (int off = 32; off; off >>= 1) acc += __shfl_down(acc, off, 64);
    if (lane == 0) dcoef[(b << 9) + o] = rsqrtf(acc + 1e-8f);
    if (blockIdx.x < 96) {
        int flat = blockIdx.x*256 + threadIdx.x;   // = b*1536 + o3*512 + c
        int bb = flat / 1536;
        int r  = flat - bb*1536;
        int c  = r & 511;
        rgbc[flat] = rgb_w[r] * s2buf[bb*512 + c];
    }
}

// ---------------- P4: Ypad[b][h+1][w+1][c] = bf16(s[b][c] * const[c][h][w])  (interior)
__global__ void k_ypad(const float* __restrict__ cst, const float* __restrict__ sbuf,
                       __hip_bfloat16* __restrict__ Ypad) {
    int b = blockIdx.x >> 6, h = blockIdx.x & 63, tid = threadIdx.x;
    __shared__ float tile[64][65];
    for (int cc = 0; cc < 8; ++cc) {
        int c0 = cc << 6;
        #pragma unroll
        for (int it = 0; it < 16; ++it) {
            int cl = (it << 2) + (tid >> 6);
            int w = tid & 63;
            tile[cl][w] = cst[(c0 + cl)*4096 + (h << 6) + w];
        }
        __syncthreads();
        #pragma unroll
        for (int it = 0; it < 16; ++it) {
            int flat = (it << 8) + tid;
            int w = flat >> 6, cl = flat & 63;
            float v = sbuf[(b << 9) + c0 + cl] * tile[cl][w];
            Ypad[(((b*66 + h + 1)*66) + (w + 1))*512 + c0 + cl] = __float2bfloat16(v);
        }
        __syncthreads();
    }
}

// ---------------- main conv GEMM: 512-thread 256x256 tile, mfma 32x32x16,
// wave tile 128x64 (4Mx2N of 32x32). 2x arithmetic intensity per LDS byte vs
// the 64x64/16x16 version (6 ds_reads feed 8 MFMAs per K-step). Counted-vmcnt
// tap pipeline + K-step-granular register frag double-buffer retained.
// A: 4-slot ring (16KB/slot), staged 3 phases ahead (2 glds/wave/phase).
// B: halo double-buffer (6x66 pos x 32c), next chunk staged on taps 0-3.
// vmcnt ledger: issue order [A,A,B]; c={3,3,3,3,2,2,2,2,2};
// VMP[T] = c[T] + Bcnt[T-1] = {3,4,4,4,3,2,2,2,2}; prologue vmcnt(2).
__global__ __launch_bounds__(512, 2) void conv_gemm(
    const short* __restrict__ Abf,   // [9][512][512] bf16
    const short* __restrict__ Ypad,  // [16][66][66][512] bf16
    const float* __restrict__ dcoef, // [16][512]
    const float* __restrict__ noise, // [4096]
    const float* __restrict__ nstr,  // [1]
    const float* __restrict__ bias,  // [512]
    const float* __restrict__ rgbc,  // [16][3][512]
    float* __restrict__ xout,        // [16][512][4096]
    float* __restrict__ img)         // [16][3][4096], pre-init to rgb_b
{
    __shared__ short Aring[32768];    // 4 slots x [256 row][32 c] swizzled (64KB)
    __shared__ short Bh2[25344];      // 2 halves x [396 pos][32 c] swizzled (50.7KB)
    __shared__ float red[256][3][2];  // ToRGB partials [n_local][o3][wr]

    int tid = threadIdx.x, lane = tid & 63, wv = tid >> 6;   // wv 0..7
    int wr = wv >> 2, wc = wv & 3;     // wave tile: rows wr*128, cols wc*64
    int ml32 = lane & 31, hi = lane >> 5;

    int blk = blockIdx.x;
    int xcd = blk & 7, idx = blk >> 3;
    int v = xcd * 64 + idx;            // bijective: 512 blocks, 64 per XCD
    int mblk = v & 1, nblk = v >> 1;   // nblk 0..255
    int b = nblk >> 4;
    int hw0 = (nblk & 15) << 8;        // 256 hw positions per block
    int h0 = hw0 >> 6;                 // top padded row of the 6-row halo window
    int o0 = mblk << 8;                // 0 or 256

    // ---- B staging: 1584 16B-slots = 3 rounds x 512 + 48 remainder
    int bgofs[3];
    #pragma unroll
    for (int r = 0; r < 3; ++r) {
        int i = tid + (r << 9);
        int pos = i >> 2;
        int hl = pos / 66;
        int ww = pos - hl*66;
        int q  = (i & 3) ^ ((pos >> 1) & 3);
        bgofs[r] = (((b*66 + h0 + hl)*66) + ww)*512 + q*8;
    }
    int pos4 = 384 + (lane >> 2);                       // lane<48 only (hl=5)
    int q4 = (lane & 3) ^ ((pos4 >> 1) & 3);
    int bg4 = ((b*66 + h0 + 5)*66 + (pos4 - 330))*512 + q4*8;

    // ---- A staging: 1024 16B-slots = 2 rounds x 512 (256 rows x 32 c)
    int agofs[2];
    #pragma unroll
    for (int r = 0; r < 2; ++r) {
        int s = tid + (r << 9);
        int row = s >> 2;
        int q = (s & 3) ^ ((row >> 1) & 3);
        agofs[r] = ((o0 + row) << 9) + q*8;
    }

    // ---- frag read precompute
    int aro[4], arx[4];
    #pragma unroll
    for (int mi = 0; mi < 4; ++mi) {
        int row = wr*128 + mi*32 + ml32;
        aro[mi] = row*32;
        arx[mi] = (row >> 1) & 3;
    }
    int pb0 = wc*66 + ml32;            // B pos base (dh=0, tl=0, ni=0)
    const int BPA[9] = {0, 1, 2, 66, 67, 68, 132, 133, 134};  // dh*66+tl per tap

    short* AW = Aring + wv*512;        // wave-uniform A write base (+slot*8192+r*4096)

    f32x16 acc[4][2] = {};
    short8 fa0[4], fb0[2], fa1[4], fb1[2];

    // ---- prologue: B chunk0 -> half0 (4 issues), A slots 0..2 (6 issues)
    #pragma unroll
    for (int r = 0; r < 3; ++r)
        glds16(Ypad + bgofs[r], Bh2 + wv*512 + r*4096);
    if (lane < 48) glds16(Ypad + bg4, Bh2 + 12288);
    #pragma unroll
    for (int t = 0; t < 3; ++t) {
        glds16(Abf + (t << 18) + agofs[0], AW + t*8192);
        glds16(Abf + (t << 18) + agofs[1], AW + t*8192 + 4096);
    }
    asm volatile("s_waitcnt vmcnt(2)" ::: "memory");    // slot2 pair may fly
    __builtin_amdgcn_s_barrier();
    // preload frags for phase (0,0) Kstep0: slot0, half0, tap0, ks=0 (q=hi)
    {
        int pos_ = pb0;
        int x_ = (pos_ >> 1) & 3;
        #pragma unroll
        for (int mi = 0; mi < 4; ++mi)
            fa0[mi] = *(const short8*)(Aring + aro[mi] + ((hi ^ arx[mi]) << 3));
        #pragma unroll
        for (int ni = 0; ni < 2; ++ni)
            fb0[ni] = *(const short8*)(Bh2 + (pos_ + ni*32)*32 + ((hi ^ x_) << 3));
    }

    const int VMP[9] = {3, 4, 4, 4, 3, 2, 2, 2, 2};

#define MMCL(FA, FB)                                                            \
    __builtin_amdgcn_s_setprio(1);                                              \
    _Pragma("unroll")                                                           \
    for (int mi = 0; mi < 4; ++mi)                                              \
        _Pragma("unroll")                                                       \
        for (int ni = 0; ni < 2; ++ni)                                          \
            acc[mi][ni] = __builtin_amdgcn_mfma_f32_32x32x16_bf16(              \
                FA[mi], FB[ni], acc[mi][ni], 0, 0, 0);                          \
    __builtin_amdgcn_s_setprio(0);

#define PHASE(TAP, HC, C0, C0N, RB)                                             \
    {                                                                           \
        int rr  = ((RB) + (TAP)) & 3;                                           \
        int rrN = ((RB) + (TAP) + 1) & 3;                                       \
        int rw  = ((RB) + (TAP) + 3) & 3;                                       \
        constexpr int TAPN = ((TAP) + 1) % 9;                                   \
        constexpr int TAPP = ((TAP) < 6) ? (TAP) + 3 : (TAP) - 6;               \
        constexpr int HN = (HC) ^ 1;                                            \
        constexpr int HRA = ((TAP) == 8) ? HN : (HC);                           \
        /* Kstep1 frags (current tap, ks=1: q=2+hi) */                          \
        { int pos_ = pb0 + BPA[(TAP)]; int x_ = (pos_ >> 1) & 3;                \
          _Pragma("unroll")                                                     \
          for (int mi = 0; mi < 4; ++mi)                                        \
              fa1[mi] = *(const short8*)(Aring + rr*8192 + aro[mi]              \
                                         + (((2 + hi) ^ arx[mi]) << 3));        \
          _Pragma("unroll")                                                     \
          for (int ni = 0; ni < 2; ++ni)                                        \
              fb1[ni] = *(const short8*)(Bh2 + (HC)*12672 + (pos_ + ni*32)*32   \
                                         + (((2 + hi) ^ x_) << 3));             \
        }                                                                       \
        /* glds: A-pair for slot rw (tap TAPP), then B round */                 \
        { const short* asrc_ = Abf + (TAPP << 18) + (((TAP) < 6) ? (C0) : (C0N)); \
          glds16(asrc_ + agofs[0], AW + rw*8192);                               \
          glds16(asrc_ + agofs[1], AW + rw*8192 + 4096); }                      \
        if ((TAP) < 3)                                                          \
            glds16(Ypad + bgofs[(TAP)] + (C0N),                                 \
                   Bh2 + HN*12672 + wv*512 + (TAP)*4096);                       \
        if ((TAP) == 3) {                                                       \
            if (lane < 48) glds16(Ypad + bg4 + (C0N), Bh2 + HN*12672 + 12288);  \
        }                                                                       \
        __builtin_amdgcn_sched_barrier(0);                                      \
        MMCL(fa0, fb0)                                                          \
        __builtin_amdgcn_sched_barrier(0);                                      \
        /* read-ahead: next phase Kstep0 (ks=0: q=hi) */                        \
        { int pos_ = pb0 + BPA[TAPN]; int x_ = (pos_ >> 1) & 3;                 \
          _Pragma("unroll")                                                     \
          for (int mi = 0; mi < 4; ++mi)                                        \
              fa0[mi] = *(const short8*)(Aring + rrN*8192 + aro[mi]             \
                                         + ((hi ^ arx[mi]) << 3));              \
          _Pragma("unroll")                                                     \
          for (int ni = 0; ni < 2; ++ni)                                        \
              fb0[ni] = *(const short8*)(Bh2 + HRA*12672 + (pos_ + ni*32)*32    \
                                         + ((hi ^ x_) << 3));                   \
        }                                                                       \
        __builtin_amdgcn_sched_barrier(0);                                      \
        MMCL(fa1, fb1)                                                          \
        asm volatile("s_waitcnt vmcnt(%0)" :: "i"(VMP[(TAP)]) : "memory");      \
        __builtin_amdgcn_s_barrier();                                           \
    }

#define CHUNK9(HC, C0, C0N, RB)                                                 \
    PHASE(0, HC, C0, C0N, RB) PHASE(1, HC, C0, C0N, RB)                         \
    PHASE(2, HC, C0, C0N, RB) PHASE(3, HC, C0, C0N, RB)                         \
    PHASE(4, HC, C0, C0N, RB) PHASE(5, HC, C0, C0N, RB)                         \
    PHASE(6, HC, C0, C0N, RB) PHASE(7, HC, C0, C0N, RB)                         \
    PHASE(8, HC, C0, C0N, RB)

    for (int cc = 0; cc < 8; ++cc) {
        int c0e = cc << 6;                 // even chunk ch=2cc -> half0
        int rbe = (cc << 1) & 3;
        CHUNK9(0, c0e, c0e + 32, rbe)
        int c0o = c0e + 32;                // odd chunk ch=2cc+1 -> half1
        int c0no = (c0e + 64) & 511;       // wraps to 0 on last chunk (dummy)
        int rbo = (rbe + 1) & 3;
        CHUNK9(1, c0o, c0no, rbo)
    }
#undef PHASE
#undef CHUNK9
#undef MMCL

    // ---------------- epilogue: demod + noise + bias + lrelu + store + fused ToRGB
    // C/D layout (32x32): col = lane&31, row = (r&3) + 8*(r>>2) + 4*hi
    float ns = nstr[0];
    float pr0[2] = {0.f, 0.f}, pr1[2] = {0.f, 0.f}, pr2[2] = {0.f, 0.f};
    #pragma unroll
    for (int mi = 0; mi < 4; ++mi) {
        int ob = o0 + wr*128 + mi*32 + hi*4;
        f32x4 dc[4], bs[4], c0r[4], c1r[4], c2r[4];
        #pragma unroll
        for (int g = 0; g < 4; ++g) {
            dc[g]  = *(const f32x4*)(dcoef + (b << 9) + ob + g*8);
            bs[g]  = *(const f32x4*)(bias + ob + g*8);
            c0r[g] = *(const f32x4*)(rgbc + b*1536 + ob + g*8);
            c1r[g] = *(const f32x4*)(rgbc + b*1536 + 512 + ob + g*8);
            c2r[g] = *(const f32x4*)(rgbc + b*1536 + 1024 + ob + g*8);
        }
        #pragma unroll
        for (int ni = 0; ni < 2; ++ni) {
            int nl = wc*64 + ni*32 + ml32;
            int hw = hw0 + nl;
            float nz = noise[hw] * ns;
            #pragma unroll
            for (int g = 0; g < 4; ++g)
                #pragma unroll
                for (int t = 0; t < 4; ++t) {
                    float vv = acc[mi][ni][g*4 + t] * dc[g][t] + nz + bs[g][t];
                    vv = (vv < 0.f ? LRELU_SLOPE*vv : vv) * ACT_GAIN;
                    xout[(((b << 9) + ob + g*8 + t) << 12) + hw] = vv;
                    pr0[ni] += vv * c0r[g][t];
                    pr1[ni] += vv * c1r[g][t];
                    pr2[ni] += vv * c2r[g][t];
                }
        }
    }
    #pragma unroll
    for (int ni = 0; ni < 2; ++ni) {
        pr0[ni] += __shfl_down(pr0[ni], 32, 64);
        pr1[ni] += __shfl_down(pr1[ni], 32, 64);
        pr2[ni] += __shfl_down(pr2[ni], 32, 64);
    }
    if (lane < 32) {
        #pragma unroll
        for (int ni = 0; ni < 2; ++ni) {
            int nl = wc*64 + ni*32 + ml32;
            red[nl][0][wr] = pr0[ni];
            red[nl][1][wr] = pr1[ni];
            red[nl][2][wr] = pr2[ni];
        }
    }
    __syncthreads();
    for (int p = tid; p < 768; p += 512) {
        int o3 = p >> 8, nl = p & 255;
        atomicAdd(img + ((b*3 + o3) << 12) + hw0 + nl, red[nl][o3][0] + red[nl][o3][1]);
    }
}

extern "C" void kernel_launch(void* const* d_in, const int* in_sizes, int n_in,
                              void* d_out, int out_size, void* d_ws, size_t ws_size,
                              hipStream_t stream) {
    (void)in_sizes; (void)n_in; (void)out_size; (void)ws_size;
    const float* wsin   = (const float*)d_in[0];   // [16][2][512]
    const float* cst    = (const float*)d_in[1];   // [512][64][64]
    const float* conv_w = (const float*)d_in[2];   // [512][512][3][3]
    const float* conv_b = (const float*)d_in[3];   // [512]
    const float* caw    = (const float*)d_in[4];   // [512][512]
    const float* cab    = (const float*)d_in[5];   // [512]
    const float* noise  = (const float*)d_in[6];   // [64][64]
    const float* nstr   = (const float*)d_in[7];   // [1]
    const float* rgb_w  = (const float*)d_in[8];   // [3][512][1][1]
    const float* rgb_b  = (const float*)d_in[9];   // [3]
    const float* raw_   = (const float*)d_in[10];  // [512][512]
    const float* rab    = (const float*)d_in[11];  // [512]

    char* wsb = (char*)d_ws;
    float* sbuf   = (float*)(wsb + 0);         // 16*512 f32
    float* s2buf  = (float*)(wsb + 32768);     // 16*512 f32
    float* dcoef  = (float*)(wsb + 65536);     // 16*512 f32
    float* rgbc   = (float*)(wsb + 98304);     // 16*3*512 f32
    float* w2sum  = (float*)(wsb + 196608);    // 512*512 f32 ([o][c])
    __hip_bfloat16* Abf  = (__hip_bfloat16*)(wsb + 1245184);  // 9*512*512 bf16
    __hip_bfloat16* Ypad = (__hip_bfloat16*)(wsb + 5963776);  // 16*66*66*512 bf16

    float* xout = (float*)d_out;               // [16][512][4096]
    float* img  = xout + 33554432;             // [16][3][4096]

    k_init<<<1088, 256, 0, stream>>>(Ypad, rgb_b, img);
    k_styles<<<dim3(16, 2), 256, 0, stream>>>(wsin, caw, cab, raw_, rab, sbuf, s2buf);
    k_prepw<<<512, 256, 0, stream>>>(conv_w, w2sum, Abf);
    k_dcoef<<<2048, 256, 0, stream>>>(sbuf, w2sum, s2buf, rgb_w, dcoef, rgbc);
    k_ypad<<<1024, 256, 0, stream>>>(cst, sbuf, Ypad);
    conv_gemm<<<512, 512, 0, stream>>>((const short*)Abf, (const short*)Ypad,
                                       dcoef, noise, nstr, conv_b, rgbc, xout, img);
}